// Round 14
// baseline (790.174 us; speedup 1.0000x reference)
//
#include <hip/hip_runtime.h>
#include <cstddef>
#include <cstdint>

#define HDIM 256
#define BSEG 4096

typedef __bf16 bf16x8 __attribute__((ext_vector_type(8)));
typedef float f32x4 __attribute__((ext_vector_type(4)));

__device__ __forceinline__ float leaky(float x) { return x >= 0.f ? x : 0.1f * x; }
__device__ __forceinline__ float bf2f(ushort u) {
    return __builtin_bit_cast(float, (uint32_t)u << 16);
}
__device__ __forceinline__ ushort f2bf(float f) {  // RNE
    uint32_t x = __builtin_bit_cast(uint32_t, f);
    return (ushort)((x + 0x7fffu + ((x >> 16) & 1u)) >> 16);
}
__device__ __forceinline__ bf16x8 pack8(float4 a, float4 b) {
    union { ushort s[8]; bf16x8 v; } u;
    u.s[0] = f2bf(a.x); u.s[1] = f2bf(a.y); u.s[2] = f2bf(a.z); u.s[3] = f2bf(a.w);
    u.s[4] = f2bf(b.x); u.s[5] = f2bf(b.y); u.s[6] = f2bf(b.z); u.s[7] = f2bf(b.w);
    return u.v;
}
__device__ __forceinline__ void store_bf4(ushort* p, float v0, float v1, float v2, float v3) {
    ushort4 o; o.x = f2bf(v0); o.y = f2bf(v1); o.z = f2bf(v2); o.w = f2bf(v3);
    *(ushort4*)p = o;
}

__device__ __forceinline__ void gld16(const ushort* g, ushort* lds) {
    __builtin_amdgcn_global_load_lds(
        (const __attribute__((address_space(1))) uint32_t*)g,
        (__attribute__((address_space(3))) uint32_t*)lds, 16, 0, 0);
}

// ---------- segment bounds (batch arrays sorted) ----------
__global__ void seg_bounds_k(const int* __restrict__ bc, const int* __restrict__ bp,
                             int* __restrict__ sc, int* __restrict__ sp, int n, int nb)
{
    int t = blockIdx.x * blockDim.x + threadIdx.x;
    if (t >= 2 * (nb + 1)) return;
    bool isc = (t <= nb);
    const int* a = isc ? bc : bp;
    int v = isc ? t : t - (nb + 1);
    int lo = 0, hi = n;
    while (lo < hi) { int mid = (lo + hi) >> 1; if (a[mid] < v) lo = mid + 1; else hi = mid; }
    if (isc) sc[t] = lo; else sp[t - (nb + 1)] = lo;
}

// ---------- 5x 256x256 weight transpose+cast, LDS-tiled ----------
__global__ __launch_bounds__(256) void wt_cast_all(
    const float* __restrict__ s0, const float* __restrict__ s1,
    const float* __restrict__ s2, const float* __restrict__ s3,
    const float* __restrict__ s4,
    ushort* __restrict__ d0, ushort* __restrict__ d1, ushort* __restrict__ d2,
    ushort* __restrict__ d3, ushort* __restrict__ d4)
{
    int m = blockIdx.x >> 4, tile = blockIdx.x & 15;
    const float* s = m == 0 ? s0 : m == 1 ? s1 : m == 2 ? s2 : m == 3 ? s3 : s4;
    ushort*      d = m == 0 ? d0 : m == 1 ? d1 : m == 2 ? d2 : m == 3 ? d3 : d4;
    int r0 = (tile >> 2) * 64, c0 = (tile & 3) * 64;
    __shared__ ushort t[64][72];
    int cc = threadIdx.x & 63, rr = threadIdx.x >> 6;
    for (int r = rr; r < 64; r += 4) t[cc][r] = f2bf(s[(size_t)(r0 + r) * 256 + c0 + cc]);
    __syncthreads();
    for (int r = rr; r < 64; r += 4) d[(size_t)(c0 + r) * 256 + r0 + cc] = t[r][cc];
}

// ---------- bf16 MFMA GEMM (R7-proven): 128x256 tile, 8 waves, dbuf LDS ----------
template<bool LEAKYACT, bool AFP32, int YT>
__global__ __launch_bounds__(512) void mg3(
    const void* __restrict__ Av, const ushort* __restrict__ WT,
    const float* __restrict__ bias0,
    ushort* __restrict__ out0)
{
    __shared__ __attribute__((aligned(16))) ushort Bs[2][256 * 32];
    __shared__ __attribute__((aligned(16))) ushort As[2][128 * 32];

    const int tid = threadIdx.x;
    const int l = tid & 63, w = tid >> 6;

    const uint nwg = gridDim.x, orig = blockIdx.x;
    const uint swz = (orig & 7) * (nwg >> 3) + (orig >> 3);   // XCD-chunked
    const int bx = (int)(swz / YT), cb = (int)(swz % YT);
    const int row0 = bx * 128, colb = cb * 256;
    (void)colb;

    const float*  Af = (const float*)Av;
    const ushort* Ah = (const ushort*)Av;

    const int sB0 = w * 128 + l;
    const int rB0 = sB0 >> 2,        rB1 = (sB0 + 64) >> 2;
    const int qB0 = (sB0 & 3) ^ ((rB0 >> 1) & 3), qB1 = ((sB0 + 64) & 3) ^ ((rB1 >> 1) & 3);
    const ushort* srcB0 = WT + (size_t)(colb + rB0) * HDIM + qB0 * 8;
    const ushort* srcB1 = WT + (size_t)(colb + rB1) * HDIM + qB1 * 8;
    const int srow = tid >> 2, sj = tid & 3;
    const int lj = sj ^ ((srow >> 1) & 3);
    const float*  fsrcA = Af + (size_t)(row0 + srow) * HDIM + lj * 8;
    const ushort* hsrcA = Ah + (size_t)(row0 + srow) * HDIM + lj * 8;

    const int wr = (w >> 2) * 64, wc = (w & 3) * 64;
    const int lr = l & 15, lt = l >> 4;

    f32x4 acc[4][4] = {};

#define STAGE_B(buf, k0) do { \
        gld16(srcB0 + (k0), &Bs[buf][sB0 * 8]); \
        gld16(srcB1 + (k0), &Bs[buf][(sB0 + 64) * 8]); \
    } while (0)

#define COMPUTE(buf) do { \
        bf16x8 af[4], bv[4]; \
        _Pragma("unroll") \
        for (int m = 0; m < 4; ++m) { \
            const int row = wr + m * 16 + lr; \
            const int q = lt ^ ((row >> 1) & 3); \
            af[m] = *(const bf16x8*)&As[buf][row * 32 + q * 8]; \
        } \
        _Pragma("unroll") \
        for (int n = 0; n < 4; ++n) { \
            const int brow = wc + n * 16 + lr; \
            const int q = lt ^ ((brow >> 1) & 3); \
            bv[n] = *(const bf16x8*)&Bs[buf][brow * 32 + q * 8]; \
        } \
        _Pragma("unroll") \
        for (int m = 0; m < 4; ++m) \
            _Pragma("unroll") \
            for (int n = 0; n < 4; ++n) \
                acc[m][n] = __builtin_amdgcn_mfma_f32_16x16x32_bf16(bv[n], af[m], acc[m][n], 0, 0, 0); \
    } while (0)

    int cur = 0;
    if (AFP32) {
        float4 av0, av1;
        av0 = *(const float4*)(fsrcA + 0);
        av1 = *(const float4*)(fsrcA + 4);
        STAGE_B(0, 0);
        *(bf16x8*)&As[0][tid * 8] = pack8(av0, av1);
        __syncthreads();
        #pragma unroll
        for (int t = 1; t < 8; ++t) {
            av0 = *(const float4*)(fsrcA + t * 32);
            av1 = *(const float4*)(fsrcA + t * 32 + 4);
            STAGE_B(cur ^ 1, t * 32);
            COMPUTE(cur);
            *(bf16x8*)&As[cur ^ 1][tid * 8] = pack8(av0, av1);
            __syncthreads();
            cur ^= 1;
        }
        COMPUTE(cur);
    } else {
        STAGE_B(0, 0);
        gld16(hsrcA, &As[0][tid * 8]);
        __syncthreads();
        #pragma unroll
        for (int t = 1; t < 8; ++t) {
            STAGE_B(cur ^ 1, t * 32);
            gld16(hsrcA + t * 32, &As[cur ^ 1][tid * 8]);
            COMPUTE(cur);
            __syncthreads();
            cur ^= 1;
        }
        COMPUTE(cur);
    }

#undef STAGE_B
#undef COMPUTE

    #pragma unroll
    for (int m = 0; m < 4; ++m) {
        const int row = row0 + wr + m * 16 + lr;
        #pragma unroll
        for (int n = 0; n < 4; ++n) {
            const int c = wc + n * 16 + (lt << 2);
            float v0 = acc[m][n][0], v1 = acc[m][n][1], v2 = acc[m][n][2], v3 = acc[m][n][3];
            float4 b4 = *(const float4*)&bias0[c];
            v0 += b4.x; v1 += b4.y; v2 += b4.z; v3 += b4.w;
            if (LEAKYACT) { v0 = leaky(v0); v1 = leaky(v1); v2 = leaky(v2); v3 = leaky(v3); }
            store_bf4(&out0[(size_t)row * HDIM + c], v0, v1, v2, v3);
        }
    }
}

// ---------- fused: e = leaky(comp@c_aff+b) -> LDS; h1 = leaky(e@W1r + gr[bc]);
//            pre = dot(leaky(e@W1a + ga[bc]), w2).  Phases 2-3 barrier-free, B from L2.
__global__ __launch_bounds__(512) void mgfused(
    const float* __restrict__ Af, const ushort* __restrict__ WTa,
    const float* __restrict__ abias,
    const ushort* __restrict__ WT2,
    const float* __restrict__ gr, const float* __restrict__ ga,
    const int* __restrict__ idx, const float* __restrict__ w2,
    ushort* __restrict__ h1, float* __restrict__ pre)
{
    __shared__ __attribute__((aligned(16))) ushort As[2][128 * 32];   // 16 KB
    __shared__ __attribute__((aligned(16))) ushort eL[8][128 * 32];   // 64 KB
    float (*pb)[4] = (float (*)[4])As;                                 // alias (As dead in phase 3)

    const int tid = threadIdx.x;
    const int l = tid & 63, w = tid >> 6;
    const uint nwg = gridDim.x, orig = blockIdx.x;
    const uint swz = (orig & 7) * (nwg >> 3) + (orig >> 3);   // XCD-chunked (nwg%8==0)
    const int row0 = (int)swz * 128;

    const int srow = tid >> 2, sj = tid & 3;
    const int lj = sj ^ ((srow >> 1) & 3);
    const float* fsrcA = Af + (size_t)(row0 + srow) * HDIM + lj * 8;

    const int wr = (w >> 2) * 64, wc = (w & 3) * 64;
    const int lr = l & 15, lt = l >> 4;

    f32x4 acc[4][4] = {};

    // ---- phase 1: e = comp @ c_aff  (A dbuf-staged, B streamed from L2 global) ----
    {
        float4 av0 = *(const float4*)(fsrcA);
        float4 av1 = *(const float4*)(fsrcA + 4);
        *(bf16x8*)&As[0][tid * 8] = pack8(av0, av1);
        __syncthreads();
        #pragma unroll
        for (int t = 0; t < 8; ++t) {
            if (t < 7) {
                av0 = *(const float4*)(fsrcA + (t + 1) * 32);
                av1 = *(const float4*)(fsrcA + (t + 1) * 32 + 4);
            }
            bf16x8 af[4], bv[4];
            #pragma unroll
            for (int m = 0; m < 4; ++m) {
                const int row = wr + m * 16 + lr;
                const int q = lt ^ ((row >> 1) & 3);
                af[m] = *(const bf16x8*)&As[t & 1][row * 32 + q * 8];
            }
            #pragma unroll
            for (int n = 0; n < 4; ++n)
                bv[n] = *(const bf16x8*)&WTa[(size_t)(wc + n * 16 + lr) * HDIM + t * 32 + lt * 8];
            #pragma unroll
            for (int m = 0; m < 4; ++m)
                #pragma unroll
                for (int n = 0; n < 4; ++n)
                    acc[m][n] = __builtin_amdgcn_mfma_f32_16x16x32_bf16(bv[n], af[m], acc[m][n], 0, 0, 0);
            if (t < 7) {
                *(bf16x8*)&As[(t + 1) & 1][tid * 8] = pack8(av0, av1);
                __syncthreads();
            }
        }
    }
    // e epilogue: bias + leaky, pack to eL in As-compatible swizzled layout
    #pragma unroll
    for (int m = 0; m < 4; ++m) {
        const int r = wr + m * 16 + lr;
        #pragma unroll
        for (int n = 0; n < 4; ++n) {
            const int c = wc + n * 16 + (lt << 2);
            float4 b4 = *(const float4*)&abias[c];
            float v0 = leaky(acc[m][n][0] + b4.x);
            float v1 = leaky(acc[m][n][1] + b4.y);
            float v2 = leaky(acc[m][n][2] + b4.z);
            float v3 = leaky(acc[m][n][3] + b4.w);
            const int ks = c >> 5, o = c & 31;
            const int s = (o >> 3) ^ ((r >> 1) & 3);
            ushort4 u; u.x = f2bf(v0); u.y = f2bf(v1); u.z = f2bf(v2); u.w = f2bf(v3);
            *(ushort4*)&eL[ks][r * 32 + s * 8 + (o & 7)] = u;
        }
    }
    __syncthreads();

    // ---- phase 2: h1 = leaky(e @ W1r + gr[bc[row]])  (barrier-free) ----
    {
        f32x4 hacc[4][4] = {};
        #pragma unroll
        for (int ks = 0; ks < 8; ++ks) {
            bf16x8 af[4], bv[4];
            #pragma unroll
            for (int m = 0; m < 4; ++m) {
                const int row = wr + m * 16 + lr;
                const int q = lt ^ ((row >> 1) & 3);
                af[m] = *(const bf16x8*)&eL[ks][row * 32 + q * 8];
            }
            #pragma unroll
            for (int n = 0; n < 4; ++n)
                bv[n] = *(const bf16x8*)&WT2[(size_t)(wc + n * 16 + lr) * HDIM + ks * 32 + lt * 8];
            #pragma unroll
            for (int m = 0; m < 4; ++m)
                #pragma unroll
                for (int n = 0; n < 4; ++n)
                    hacc[m][n] = __builtin_amdgcn_mfma_f32_16x16x32_bf16(bv[n], af[m], hacc[m][n], 0, 0, 0);
        }
        #pragma unroll
        for (int m = 0; m < 4; ++m) {
            const int row = row0 + wr + m * 16 + lr;
            const float* rrow = gr + (size_t)idx[row] * HDIM;
            #pragma unroll
            for (int n = 0; n < 4; ++n) {
                const int c = wc + n * 16 + (lt << 2);
                float4 r4 = *(const float4*)&rrow[c];
                store_bf4(&h1[(size_t)row * HDIM + c],
                          leaky(hacc[m][n][0] + r4.x), leaky(hacc[m][n][1] + r4.y),
                          leaky(hacc[m][n][2] + r4.z), leaky(hacc[m][n][3] + r4.w));
            }
        }
    }

    // ---- phase 3: alpha dot (barrier-free MFMA, then cross-wave LDS reduce) ----
    {
        f32x4 aacc[4][4] = {};
        #pragma unroll
        for (int ks = 0; ks < 8; ++ks) {
            bf16x8 af[4], bv[4];
            #pragma unroll
            for (int m = 0; m < 4; ++m) {
                const int row = wr + m * 16 + lr;
                const int q = lt ^ ((row >> 1) & 3);
                af[m] = *(const bf16x8*)&eL[ks][row * 32 + q * 8];
            }
            #pragma unroll
            for (int n = 0; n < 4; ++n)
                bv[n] = *(const bf16x8*)&WT2[(size_t)(256 + wc + n * 16 + lr) * HDIM + ks * 32 + lt * 8];
            #pragma unroll
            for (int m = 0; m < 4; ++m)
                #pragma unroll
                for (int n = 0; n < 4; ++n)
                    aacc[m][n] = __builtin_amdgcn_mfma_f32_16x16x32_bf16(bv[n], af[m], aacc[m][n], 0, 0, 0);
        }
        __syncthreads();   // As (aliased as pb) fully dead for all waves
        #pragma unroll
        for (int m = 0; m < 4; ++m) {
            const int row = row0 + wr + m * 16 + lr;
            const float* rrow = ga + (size_t)idx[row] * HDIM;
            float p = 0.f;
            #pragma unroll
            for (int n = 0; n < 4; ++n) {
                const int c = wc + n * 16 + (lt << 2);
                float4 r4 = *(const float4*)&rrow[c];
                float4 w4 = *(const float4*)&w2[c];
                p += leaky(aacc[m][n][0] + r4.x) * w4.x;
                p += leaky(aacc[m][n][1] + r4.y) * w4.y;
                p += leaky(aacc[m][n][2] + r4.z) * w4.z;
                p += leaky(aacc[m][n][3] + r4.w) * w4.w;
            }
            p += __shfl_xor(p, 16);
            p += __shfl_xor(p, 32);
            if (lt == 0) pb[wr + m * 16 + lr][w & 3] = p;
        }
        __syncthreads();
        if (tid < 128) pre[row0 + tid] = pb[tid][0] + pb[tid][1] + pb[tid][2] + pb[tid][3];
    }
}

// ---------- fp32 dual GEMM for gr/ga: z picks the weight/bias set ----------
__global__ __launch_bounds__(256) void gemm64_2(
    const float* __restrict__ A, const float* __restrict__ A2,
    const float* __restrict__ Wb_r, const float* __restrict__ Wc_r, const float* __restrict__ bias_r,
    const float* __restrict__ Wb_a, const float* __restrict__ Wc_a, const float* __restrict__ bias_a,
    float* __restrict__ Cr, float* __restrict__ Ca)
{
    const int K = HDIM, NO = HDIM;
    const float* W  = blockIdx.z ? Wb_a : Wb_r;
    const float* W2 = blockIdx.z ? Wc_a : Wc_r;
    const float* bias = blockIdx.z ? bias_a : bias_r;
    float* C = blockIdx.z ? Ca : Cr;

    __shared__ float As [16][68];
    __shared__ float Bs [16][68];
    __shared__ float As2[16][68];
    __shared__ float Bs2[16][68];

    const int tid = threadIdx.x;
    const int tx = tid & 15, ty = tid >> 4;
    const int row0 = blockIdx.x * 64, col0 = blockIdx.y * 64;

    const int lr = tid >> 2;
    const int lk = (tid & 3) << 2;
    const int bk = tid >> 4;
    const int bj = (tid & 15) << 2;

    float acc[4][4] = {};

    for (int k0 = 0; k0 < K; k0 += 16) {
        float4 a4 = *(const float4*)&A[(size_t)(row0 + lr) * K + k0 + lk];
        As[lk + 0][lr] = a4.x; As[lk + 1][lr] = a4.y;
        As[lk + 2][lr] = a4.z; As[lk + 3][lr] = a4.w;
        *(float4*)&Bs[bk][bj] = *(const float4*)&W[(size_t)(k0 + bk) * NO + col0 + bj];
        float4 c4 = *(const float4*)&A2[(size_t)(row0 + lr) * K + k0 + lk];
        As2[lk + 0][lr] = c4.x; As2[lk + 1][lr] = c4.y;
        As2[lk + 2][lr] = c4.z; As2[lk + 3][lr] = c4.w;
        *(float4*)&Bs2[bk][bj] = *(const float4*)&W2[(size_t)(k0 + bk) * NO + col0 + bj];
        __syncthreads();
        #pragma unroll
        for (int kk = 0; kk < 16; ++kk) {
            float4 av = *(const float4*)&As[kk][ty << 2];
            float4 bv = *(const float4*)&Bs[kk][tx << 2];
            float a_[4] = {av.x, av.y, av.z, av.w};
            float b_[4] = {bv.x, bv.y, bv.z, bv.w};
            #pragma unroll
            for (int i = 0; i < 4; ++i)
                #pragma unroll
                for (int j = 0; j < 4; ++j)
                    acc[i][j] += a_[i] * b_[j];
            float4 av2 = *(const float4*)&As2[kk][ty << 2];
            float4 bv2 = *(const float4*)&Bs2[kk][tx << 2];
            float c_[4] = {av2.x, av2.y, av2.z, av2.w};
            float d_[4] = {bv2.x, bv2.y, bv2.z, bv2.w};
            #pragma unroll
            for (int i = 0; i < 4; ++i)
                #pragma unroll
                for (int j = 0; j < 4; ++j)
                    acc[i][j] += c_[i] * d_[j];
        }
        __syncthreads();
    }

    #pragma unroll
    for (int i = 0; i < 4; ++i) {
        int row = row0 + (ty << 2) + i;
        float vv[4];
        #pragma unroll
        for (int j = 0; j < 4; ++j) {
            int col = col0 + (tx << 2) + j;
            vv[j] = acc[i][j] + bias[col];
        }
        float4 o; o.x = vv[0]; o.y = vv[1]; o.z = vv[2]; o.w = vv[3];
        *(float4*)&C[(size_t)row * NO + col0 + (tx << 2)] = o;
    }
}

// ---------- per-segment column reduce, 16B/lane (sum or max) ----------
template<bool ISMAX>
__global__ __launch_bounds__(256) void seg_reduce8(const ushort* __restrict__ in,
        const int* __restrict__ starts, float* __restrict__ out)
{
    __shared__ float part[8][HDIM];
    const int b = blockIdx.x, tid = threadIdx.x;
    const int sub = tid & 31, r = tid >> 5;
    const int s = starts[b], e = starts[b + 1];
    float a[8];
    #pragma unroll
    for (int j = 0; j < 8; ++j) a[j] = ISMAX ? -INFINITY : 0.f;
    for (int i = s + r; i < e; i += 8) {
        uint4 v = *(const uint4*)&in[(size_t)i * HDIM + sub * 8];
        float f[8] = { bf2f((ushort)v.x), bf2f((ushort)(v.x >> 16)),
                       bf2f((ushort)v.y), bf2f((ushort)(v.y >> 16)),
                       bf2f((ushort)v.z), bf2f((ushort)(v.z >> 16)),
                       bf2f((ushort)v.w), bf2f((ushort)(v.w >> 16)) };
        #pragma unroll
        for (int j = 0; j < 8; ++j) a[j] = ISMAX ? fmaxf(a[j], f[j]) : (a[j] + f[j]);
    }
    #pragma unroll
    for (int j = 0; j < 8; ++j) part[r][sub * 8 + j] = a[j];
    __syncthreads();
    float res = part[0][tid];
    #pragma unroll
    for (int j = 1; j < 8; ++j) res = ISMAX ? fmaxf(res, part[j][tid]) : (res + part[j][tid]);
    out[(size_t)b * HDIM + tid] = res;
}

// ---------- scatter softmax; also emits sa[b] = S/(S+1e-6) ----------
__global__ __launch_bounds__(64) void seg_softmax_k(const float* __restrict__ pre,
        const int* __restrict__ starts, float* __restrict__ alpha, float* __restrict__ sa)
{
    int b = blockIdx.x, lane = threadIdx.x;
    int s = starts[b], e = starts[b + 1];
    float m = -INFINITY;
    for (int i = s + lane; i < e; i += 64) m = fmaxf(m, pre[i]);
    #pragma unroll
    for (int off = 32; off; off >>= 1) m = fmaxf(m, __shfl_xor(m, off));
    float S = 0.f;
    for (int i = s + lane; i < e; i += 64) S += expf(pre[i] - m);
    #pragma unroll
    for (int off = 32; off; off >>= 1) S += __shfl_xor(S, off);
    float denom = S + 1e-6f;
    if (lane == 0) sa[b] = S / denom;
    for (int i = s + lane; i < e; i += 64) alpha[i] = expf(pre[i] - m) / denom;
}

// ---------- hw[b,:] = sum h1[i,:]*alpha[i], 16B/lane ----------
__global__ __launch_bounds__(256) void seg_wsum8(const ushort* __restrict__ raw,
        const float* __restrict__ alpha, const int* __restrict__ starts,
        float* __restrict__ vec)
{
    __shared__ float part[8][HDIM];
    const int b = blockIdx.x, tid = threadIdx.x;
    const int sub = tid & 31, r = tid >> 5;
    const int s = starts[b], e = starts[b + 1];
    float a[8] = {};
    for (int i = s + r; i < e; i += 8) {
        float al = alpha[i];
        uint4 v = *(const uint4*)&raw[(size_t)i * HDIM + sub * 8];
        a[0] += bf2f((ushort)v.x) * al;        a[1] += bf2f((ushort)(v.x >> 16)) * al;
        a[2] += bf2f((ushort)v.y) * al;        a[3] += bf2f((ushort)(v.y >> 16)) * al;
        a[4] += bf2f((ushort)v.z) * al;        a[5] += bf2f((ushort)(v.z >> 16)) * al;
        a[6] += bf2f((ushort)v.w) * al;        a[7] += bf2f((ushort)(v.w >> 16)) * al;
    }
    #pragma unroll
    for (int j = 0; j < 8; ++j) part[r][sub * 8 + j] = a[j];
    __syncthreads();
    float res = 0.f;
    #pragma unroll
    for (int j = 0; j < 8; ++j) res += part[j][tid];
    vec[(size_t)b * HDIM + tid] = res;
}

// ---------- final: vector = hw@raw_W2 + raw_b2*sa; affinity head ----------
__global__ __launch_bounds__(256) void final_k(
    const float* __restrict__ hw, const float* __restrict__ sa,
    const float* __restrict__ W2r, const float* __restrict__ rb2,
    const float* __restrict__ oW1, const float* __restrict__ ob1,
    const float* __restrict__ oW2, const float* __restrict__ ob2,
    float* __restrict__ out_vec, float* __restrict__ out_aff)
{
    __shared__ float v[HDIM];
    __shared__ float vecs[HDIM];
    __shared__ float red[4];
    int b = blockIdx.x, t = threadIdx.x;
    v[t] = hw[(size_t)b * HDIM + t];
    __syncthreads();
    float a = rb2[t] * sa[b];
    #pragma unroll 8
    for (int k = 0; k < HDIM; ++k) a += v[k] * W2r[(size_t)k * HDIM + t];
    out_vec[(size_t)b * HDIM + t] = a;
    vecs[t] = a;
    __syncthreads();
    float h = ob1[t];
    #pragma unroll 8
    for (int k = 0; k < HDIM; ++k) h += vecs[k] * oW1[(size_t)k * HDIM + t];
    h = leaky(h);
    float p = h * oW2[t];
    #pragma unroll
    for (int off = 32; off; off >>= 1) p += __shfl_down(p, off);
    int lane = t & 63, wid = t >> 6;
    if (lane == 0) red[wid] = p;
    __syncthreads();
    if (t == 0) out_aff[b] = red[0] + red[1] + red[2] + red[3] + ob2[0];
}

extern "C" void kernel_launch(void* const* d_in, const int* in_sizes, int n_in,
                              void* d_out, int out_size, void* d_ws, size_t ws_size,
                              hipStream_t stream)
{
    const int N = in_sizes[2];
    const int H = HDIM;
    const int B = BSEG;

    const float* comp   = (const float*)d_in[0];
    const float* prot   = (const float*)d_in[1];
    const int*   bc     = (const int*)d_in[2];
    const int*   bp     = (const int*)d_in[3];
    const float* c_aff_W = (const float*)d_in[4];
    const float* c_aff_b = (const float*)d_in[5];
    const float* c_sup_W = (const float*)d_in[6];
    const float* c_sup_b = (const float*)d_in[7];
    const float* p_aff_W = (const float*)d_in[8];
    const float* p_aff_b = (const float*)d_in[9];
    const float* raw_W1  = (const float*)d_in[10];
    const float* raw_b1  = (const float*)d_in[11];
    const float* raw_W2  = (const float*)d_in[12];
    const float* raw_b2  = (const float*)d_in[13];
    const float* alpha_W1 = (const float*)d_in[14];
    const float* alpha_b1 = (const float*)d_in[15];
    const float* alpha_W2 = (const float*)d_in[16];
    const float* out_W1  = (const float*)d_in[18];
    const float* out_b1  = (const float*)d_in[19];
    const float* out_W2  = (const float*)d_in[20];
    const float* out_b2  = (const float*)d_in[21];

    const size_t NBIG = (size_t)N * H;
    const size_t SSEG = (size_t)B * H;

    char* p = (char*)d_ws;
    ushort* e2 = (ushort*)p; p += NBIG * 2;   // csup bf16
    ushort* e3 = (ushort*)p; p += NBIG * 2;   // prot_emb bf16 -> h1 (hid_raw)
    float* supe = (float*)p;  p += SSEG * 4;
    float* pool = (float*)p;  p += SSEG * 4;
    float* gr   = (float*)p;  p += SSEG * 4;
    float* ga   = (float*)p;  p += SSEG * 4;
    float* hw   = (float*)p;  p += SSEG * 4;  // weighted sum of h1
    float* sa   = (float*)p;  p += (size_t)B * 4;
    float* pre  = (float*)p;  p += (size_t)N * 4;
    ushort* WTa = (ushort*)p; p += (size_t)256 * 256 * 2;  // c_aff^T
    ushort* WTs = (ushort*)p; p += (size_t)256 * 256 * 2;  // c_sup^T
    ushort* WTp = (ushort*)p; p += (size_t)256 * 256 * 2;  // p_aff^T
    ushort* WT2 = (ushort*)p; p += (size_t)512 * 256 * 2;  // [raw_W1[0:256]^T ; alpha_W1[0:256]^T]
    int* sc = (int*)p; p += (size_t)(B + 1) * 4;
    int* sp = (int*)p; p += (size_t)(B + 1) * 4;
    if ((size_t)(p - (char*)d_ws) > ws_size) return;

    ushort* h1 = e3;   // hid_raw (e3 dead after pool)

    float* out_vec   = (float*)d_out;
    float* out_alpha = out_vec + SSEG;
    float* out_aff   = out_alpha + N;

    dim3 blk(256), blk5(512);

    seg_bounds_k<<<(2 * (B + 1) + 255) / 256, blk, 0, stream>>>(bc, bp, sc, sp, N, B);
    wt_cast_all<<<5 * 16, blk, 0, stream>>>(
        c_aff_W, c_sup_W, p_aff_W, raw_W1, alpha_W1,
        WTa, WTs, WTp, WT2, WT2 + 65536);

    // G1': e2 = leaky(comp @ c_sup + b)
    mg3<true, true, 1><<<dim3(N / 128), blk5, 0, stream>>>(comp, WTs, c_sup_b, e2);
    // G2: e3 = leaky(prot @ p_aff + b)
    mg3<true, true, 1><<<dim3(N / 128), blk5, 0, stream>>>(prot, WTp, p_aff_b, e3);
    // pools
    seg_reduce8<false><<<B, blk, 0, stream>>>(e2, sc, supe);
    seg_reduce8<true ><<<B, blk, 0, stream>>>(e3, sp, pool);
    // gr/ga = supe@W1[256:512] + pool@W1[512:768] + b1
    gemm64_2<<<dim3(B / 64, 4, 2), blk, 0, stream>>>(supe, pool,
        raw_W1 + H * H, raw_W1 + 2 * H * H, raw_b1,
        alpha_W1 + H * H, alpha_W1 + 2 * H * H, alpha_b1, gr, ga);
    // fused: e (in LDS) -> h1 + alpha-dot  (one comp read, no e1 round-trip)
    mgfused<<<dim3(N / 128), blk5, 0, stream>>>(
        comp, WTa, c_aff_b, WT2, gr, ga, bc, alpha_W2, h1, pre);
    // softmax -> alpha + sa  (alpha_b2 cancels exactly)
    seg_softmax_k<<<B, dim3(64), 0, stream>>>(pre, sc, out_alpha, sa);
    // hw = seg_wsum(alpha * h1)
    seg_wsum8<<<B, blk, 0, stream>>>(h1, out_alpha, sc, hw);
    // vector = hw @ raw_W2 + raw_b2*sa ; affinity head
    final_k<<<B, blk, 0, stream>>>(hw, sa, raw_W2, raw_b2,
        out_W1, out_b1, out_W2, out_b2, out_vec, out_aff);
}

// Round 15
// 690.688 us; speedup vs baseline: 1.1440x; 1.1440x over previous
//
#include <hip/hip_runtime.h>
#include <cstddef>
#include <cstdint>

#define HDIM 256
#define BSEG 4096

typedef __bf16 bf16x8 __attribute__((ext_vector_type(8)));
typedef float f32x4 __attribute__((ext_vector_type(4)));

__device__ __forceinline__ float leaky(float x) { return x >= 0.f ? x : 0.1f * x; }
__device__ __forceinline__ float bf2f(ushort u) {
    return __builtin_bit_cast(float, (uint32_t)u << 16);
}
__device__ __forceinline__ ushort f2bf(float f) {  // RNE
    uint32_t x = __builtin_bit_cast(uint32_t, f);
    return (ushort)((x + 0x7fffu + ((x >> 16) & 1u)) >> 16);
}
__device__ __forceinline__ bf16x8 pack8(float4 a, float4 b) {
    union { ushort s[8]; bf16x8 v; } u;
    u.s[0] = f2bf(a.x); u.s[1] = f2bf(a.y); u.s[2] = f2bf(a.z); u.s[3] = f2bf(a.w);
    u.s[4] = f2bf(b.x); u.s[5] = f2bf(b.y); u.s[6] = f2bf(b.z); u.s[7] = f2bf(b.w);
    return u.v;
}
__device__ __forceinline__ void store_bf4(ushort* p, float v0, float v1, float v2, float v3) {
    ushort4 o; o.x = f2bf(v0); o.y = f2bf(v1); o.z = f2bf(v2); o.w = f2bf(v3);
    *(ushort4*)p = o;
}
__device__ __forceinline__ void gld16(const ushort* g, ushort* lds) {
    __builtin_amdgcn_global_load_lds(
        (const __attribute__((address_space(1))) uint32_t*)g,
        (__attribute__((address_space(3))) uint32_t*)lds, 16, 0, 0);
}
// monotone float<->int key (order-preserving incl. negatives); exact
__device__ __forceinline__ int fkey(float f) {
    int b = __builtin_bit_cast(int, f);
    return b >= 0 ? b : b ^ 0x7fffffff;
}

// ---------- segment bounds (batch arrays sorted) ----------
__global__ void seg_bounds_k(const int* __restrict__ bc, const int* __restrict__ bp,
                             int* __restrict__ sc, int* __restrict__ sp, int n, int nb)
{
    int t = blockIdx.x * blockDim.x + threadIdx.x;
    if (t >= 2 * (nb + 1)) return;
    bool isc = (t <= nb);
    const int* a = isc ? bc : bp;
    int v = isc ? t : t - (nb + 1);
    int lo = 0, hi = n;
    while (lo < hi) { int mid = (lo + hi) >> 1; if (a[mid] < v) lo = mid + 1; else hi = mid; }
    if (isc) sc[t] = lo; else sp[t - (nb + 1)] = lo;
}

// ---------- 5x 256x256 weight transpose+cast, LDS-tiled ----------
__global__ __launch_bounds__(256) void wt_cast_all(
    const float* __restrict__ s0, const float* __restrict__ s1,
    const float* __restrict__ s2, const float* __restrict__ s3,
    const float* __restrict__ s4,
    ushort* __restrict__ d0, ushort* __restrict__ d1, ushort* __restrict__ d2,
    ushort* __restrict__ d3, ushort* __restrict__ d4)
{
    int m = blockIdx.x >> 4, tile = blockIdx.x & 15;
    const float* s = m == 0 ? s0 : m == 1 ? s1 : m == 2 ? s2 : m == 3 ? s3 : s4;
    ushort*      d = m == 0 ? d0 : m == 1 ? d1 : m == 2 ? d2 : m == 3 ? d3 : d4;
    int r0 = (tile >> 2) * 64, c0 = (tile & 3) * 64;
    __shared__ ushort t[64][72];
    int cc = threadIdx.x & 63, rr = threadIdx.x >> 6;
    for (int r = rr; r < 64; r += 4) t[cc][r] = f2bf(s[(size_t)(r0 + r) * 256 + c0 + cc]);
    __syncthreads();
    for (int r = rr; r < 64; r += 4) d[(size_t)(c0 + r) * 256 + r0 + cc] = t[r][cc];
}

// ---------- init supe=0, pooli=fkey(-inf); grid = B*H/256 ----------
__global__ __launch_bounds__(256) void init_red_k(float* __restrict__ supe, int* __restrict__ pooli)
{
    int i = blockIdx.x * 256 + threadIdx.x;
    supe[i] = 0.f;
    pooli[i] = (int)0x807fffff;   // fkey(-inf)
}
__global__ __launch_bounds__(256) void unmap_pool_k(const int* __restrict__ pooli, float* __restrict__ pool)
{
    int i = blockIdx.x * 256 + threadIdx.x;
    int k = pooli[i];
    int b = k >= 0 ? k : k ^ 0x7fffffff;
    pool[i] = __builtin_bit_cast(float, b);
}

// ---------- bf16 MFMA GEMM (R7-proven core): 128x256 tile, 8 waves, dbuf LDS ----------
// MODE 0 (G1): fp32 A, YT=2. cb0: e1 = leaky(A@Waff + bias0) stored.
//              cb1: segment_sum(leaky(A@Wsup + bias1)) -> atomicAdd supe (no store).
// MODE 1 (G2): fp32 A, YT=1. segment_max(leaky(A@Wp + bias0)) -> atomicMax pooli.
// MODE 2 (G3): bf16 A, YT=2. cb0: h1 = leaky(A@W1r + rt0[idx]); cb1: alpha-dot -> pre.
template<int MODE>
__global__ __launch_bounds__(512) void mgx(
    const void* __restrict__ Av, const ushort* __restrict__ WT,
    const float* __restrict__ bias0, const float* __restrict__ bias1,
    const float* __restrict__ rt0, const float* __restrict__ rt1,
    const int* __restrict__ idx,
    ushort* __restrict__ out0,
    float* __restrict__ supe, int* __restrict__ pooli,
    const float* __restrict__ w2, float* __restrict__ pre)
{
    constexpr bool AFP32 = (MODE != 2);
    constexpr int YT = (MODE == 1) ? 1 : 2;

    __shared__ __attribute__((aligned(16))) ushort Bs[2][256 * 32];
    __shared__ __attribute__((aligned(16))) ushort As[2][128 * 32];
    __shared__ float pb[128][4];

    const int tid = threadIdx.x;
    const int l = tid & 63, w = tid >> 6;

    const uint nwg = gridDim.x, orig = blockIdx.x;
    const uint swz = (orig & 7) * (nwg >> 3) + (orig >> 3);   // XCD-chunked (nwg%8==0)
    const int bx = (int)(swz / YT), cb = (int)(swz % YT);
    const int row0 = bx * 128, colb = cb * 256;

    const float*  Af = (const float*)Av;
    const ushort* Ah = (const ushort*)Av;

    // --- B staging: 1024 slots of 16B (4 per 32-elem row), source pre-swizzled ---
    const int sB0 = w * 128 + l;
    const int rB0 = sB0 >> 2,        rB1 = (sB0 + 64) >> 2;
    const int qB0 = (sB0 & 3) ^ ((rB0 >> 1) & 3), qB1 = ((sB0 + 64) & 3) ^ ((rB1 >> 1) & 3);
    const ushort* srcB0 = WT + (size_t)(colb + rB0) * HDIM + qB0 * 8;
    const ushort* srcB1 = WT + (size_t)(colb + rB1) * HDIM + qB1 * 8;
    // --- A staging: 512 slots (4 per row), slot (srow, sj) holds chunk sj^((srow>>1)&3) ---
    const int srow = tid >> 2, sj = tid & 3;
    const int lj = sj ^ ((srow >> 1) & 3);
    const float*  fsrcA = Af + (size_t)(row0 + srow) * HDIM + lj * 8;
    const ushort* hsrcA = Ah + (size_t)(row0 + srow) * HDIM + lj * 8;

    const int wr = (w >> 2) * 64, wc = (w & 3) * 64;
    const int lr = l & 15, lt = l >> 4;

    f32x4 acc[4][4] = {};

#define STAGE_B(buf, k0) do { \
        gld16(srcB0 + (k0), &Bs[buf][sB0 * 8]); \
        gld16(srcB1 + (k0), &Bs[buf][(sB0 + 64) * 8]); \
    } while (0)

#define COMPUTE(buf) do { \
        bf16x8 af[4], bv[4]; \
        _Pragma("unroll") \
        for (int m = 0; m < 4; ++m) { \
            const int row = wr + m * 16 + lr; \
            const int q = lt ^ ((row >> 1) & 3); \
            af[m] = *(const bf16x8*)&As[buf][row * 32 + q * 8]; \
        } \
        _Pragma("unroll") \
        for (int n = 0; n < 4; ++n) { \
            const int brow = wc + n * 16 + lr; \
            const int q = lt ^ ((brow >> 1) & 3); \
            bv[n] = *(const bf16x8*)&Bs[buf][brow * 32 + q * 8]; \
        } \
        _Pragma("unroll") \
        for (int m = 0; m < 4; ++m) \
            _Pragma("unroll") \
            for (int n = 0; n < 4; ++n) \
                acc[m][n] = __builtin_amdgcn_mfma_f32_16x16x32_bf16(bv[n], af[m], acc[m][n], 0, 0, 0); \
    } while (0)

    int cur = 0;
    if (AFP32) {
        float4 av0, av1;
        av0 = *(const float4*)(fsrcA + 0);
        av1 = *(const float4*)(fsrcA + 4);
        STAGE_B(0, 0);
        *(bf16x8*)&As[0][tid * 8] = pack8(av0, av1);
        __syncthreads();
        #pragma unroll
        for (int t = 1; t < 8; ++t) {
            av0 = *(const float4*)(fsrcA + t * 32);
            av1 = *(const float4*)(fsrcA + t * 32 + 4);
            STAGE_B(cur ^ 1, t * 32);
            COMPUTE(cur);
            *(bf16x8*)&As[cur ^ 1][tid * 8] = pack8(av0, av1);
            __syncthreads();
            cur ^= 1;
        }
        COMPUTE(cur);
    } else {
        STAGE_B(0, 0);
        gld16(hsrcA, &As[0][tid * 8]);
        __syncthreads();
        #pragma unroll
        for (int t = 1; t < 8; ++t) {
            STAGE_B(cur ^ 1, t * 32);
            gld16(hsrcA + t * 32, &As[cur ^ 1][tid * 8]);
            COMPUTE(cur);
            __syncthreads();
            cur ^= 1;
        }
        COMPUTE(cur);
    }

#undef STAGE_B
#undef COMPUTE

    if (MODE == 0 && cb == 0) {
        // e1 = leaky(acc + bias0), stored
        #pragma unroll
        for (int m = 0; m < 4; ++m) {
            const int row = row0 + wr + m * 16 + lr;
            #pragma unroll
            for (int n = 0; n < 4; ++n) {
                const int c = wc + n * 16 + (lt << 2);
                float4 b4 = *(const float4*)&bias0[c];
                store_bf4(&out0[(size_t)row * HDIM + c],
                          leaky(acc[m][n][0] + b4.x), leaky(acc[m][n][1] + b4.y),
                          leaky(acc[m][n][2] + b4.z), leaky(acc[m][n][3] + b4.w));
            }
        }
    } else if (MODE == 0 || MODE == 1) {
        // fused segment reduction: lanes lr=0..15 of each 16-lane partition hold
        // 16 CONSECUTIVE sorted rows -> segmented scan, last-of-segment emits atomic.
        const float* bias = (MODE == 0) ? bias1 : bias0;
        #pragma unroll
        for (int m = 0; m < 4; ++m) {
            const int row = row0 + wr + m * 16 + lr;
            const int seg = idx[row];
            bool take[4];
            #pragma unroll
            for (int k = 0; k < 4; ++k) {
                int so = __shfl_up(seg, 1 << k, 16);
                take[k] = (lr >= (1 << k)) && (so == seg);
            }
            int segdn = __shfl_down(seg, 1, 16);
            const bool last = (lr == 15) || (segdn != seg);
            #pragma unroll
            for (int n = 0; n < 4; ++n) {
                const int c = wc + n * 16 + (lt << 2);
                float4 b4 = *(const float4*)&bias[c];
                float v[4] = { leaky(acc[m][n][0] + b4.x), leaky(acc[m][n][1] + b4.y),
                               leaky(acc[m][n][2] + b4.z), leaky(acc[m][n][3] + b4.w) };
                #pragma unroll
                for (int j = 0; j < 4; ++j) {
                    float x = v[j];
                    #pragma unroll
                    for (int k = 0; k < 4; ++k) {
                        float o = __shfl_up(x, 1 << k, 16);
                        if (MODE == 0) { if (take[k]) x += o; }
                        else           { if (take[k]) x = fmaxf(x, o); }
                    }
                    if (last) {
                        if (MODE == 0) atomicAdd(&supe[(size_t)seg * HDIM + c + j], x);
                        else           atomicMax(&pooli[(size_t)seg * HDIM + c + j], fkey(x));
                    }
                }
            }
        }
    } else if (MODE == 2 && cb == 1) {
        // alpha-dot: hidden = leaky(acc + rt1[idx[row]]); pre[row] = dot(hidden, w2)
        #pragma unroll
        for (int m = 0; m < 4; ++m) {
            const int row = row0 + wr + m * 16 + lr;
            const float* rrow = rt1 + (size_t)idx[row] * HDIM;
            float p = 0.f;
            #pragma unroll
            for (int n = 0; n < 4; ++n) {
                const int c = wc + n * 16 + (lt << 2);
                float4 r4 = *(const float4*)&rrow[c];
                float4 w4 = *(const float4*)&w2[c];
                p += leaky(acc[m][n][0] + r4.x) * w4.x;
                p += leaky(acc[m][n][1] + r4.y) * w4.y;
                p += leaky(acc[m][n][2] + r4.z) * w4.z;
                p += leaky(acc[m][n][3] + r4.w) * w4.w;
            }
            p += __shfl_xor(p, 16);
            p += __shfl_xor(p, 32);
            if (lt == 0) pb[wr + m * 16 + lr][w & 3] = p;
        }
        __syncthreads();
        if (tid < 128) pre[row0 + tid] = pb[tid][0] + pb[tid][1] + pb[tid][2] + pb[tid][3];
    } else {
        // MODE 2 cb0: h1 = leaky(acc + rt0[idx[row]]), stored
        #pragma unroll
        for (int m = 0; m < 4; ++m) {
            const int row = row0 + wr + m * 16 + lr;
            const float* rrow = rt0 + (size_t)idx[row] * HDIM;
            #pragma unroll
            for (int n = 0; n < 4; ++n) {
                const int c = wc + n * 16 + (lt << 2);
                float4 r4 = *(const float4*)&rrow[c];
                store_bf4(&out0[(size_t)row * HDIM + c],
                          leaky(acc[m][n][0] + r4.x), leaky(acc[m][n][1] + r4.y),
                          leaky(acc[m][n][2] + r4.z), leaky(acc[m][n][3] + r4.w));
            }
        }
    }
}

// ---------- fp32 dual GEMM for gr/ga: z picks the weight/bias set ----------
__global__ __launch_bounds__(256) void gemm64_2(
    const float* __restrict__ A, const float* __restrict__ A2,
    const float* __restrict__ Wb_r, const float* __restrict__ Wc_r, const float* __restrict__ bias_r,
    const float* __restrict__ Wb_a, const float* __restrict__ Wc_a, const float* __restrict__ bias_a,
    float* __restrict__ Cr, float* __restrict__ Ca)
{
    const int K = HDIM, NO = HDIM;
    const float* W  = blockIdx.z ? Wb_a : Wb_r;
    const float* W2 = blockIdx.z ? Wc_a : Wc_r;
    const float* bias = blockIdx.z ? bias_a : bias_r;
    float* C = blockIdx.z ? Ca : Cr;

    __shared__ float As [16][68];
    __shared__ float Bs [16][68];
    __shared__ float As2[16][68];
    __shared__ float Bs2[16][68];

    const int tid = threadIdx.x;
    const int tx = tid & 15, ty = tid >> 4;
    const int row0 = blockIdx.x * 64, col0 = blockIdx.y * 64;

    const int lr = tid >> 2;
    const int lk = (tid & 3) << 2;
    const int bk = tid >> 4;
    const int bj = (tid & 15) << 2;

    float acc[4][4] = {};

    for (int k0 = 0; k0 < K; k0 += 16) {
        float4 a4 = *(const float4*)&A[(size_t)(row0 + lr) * K + k0 + lk];
        As[lk + 0][lr] = a4.x; As[lk + 1][lr] = a4.y;
        As[lk + 2][lr] = a4.z; As[lk + 3][lr] = a4.w;
        *(float4*)&Bs[bk][bj] = *(const float4*)&W[(size_t)(k0 + bk) * NO + col0 + bj];
        float4 c4 = *(const float4*)&A2[(size_t)(row0 + lr) * K + k0 + lk];
        As2[lk + 0][lr] = c4.x; As2[lk + 1][lr] = c4.y;
        As2[lk + 2][lr] = c4.z; As2[lk + 3][lr] = c4.w;
        *(float4*)&Bs2[bk][bj] = *(const float4*)&W2[(size_t)(k0 + bk) * NO + col0 + bj];
        __syncthreads();
        #pragma unroll
        for (int kk = 0; kk < 16; ++kk) {
            float4 av = *(const float4*)&As[kk][ty << 2];
            float4 bv = *(const float4*)&Bs[kk][tx << 2];
            float a_[4] = {av.x, av.y, av.z, av.w};
            float b_[4] = {bv.x, bv.y, bv.z, bv.w};
            #pragma unroll
            for (int i = 0; i < 4; ++i)
                #pragma unroll
                for (int j = 0; j < 4; ++j)
                    acc[i][j] += a_[i] * b_[j];
            float4 av2 = *(const float4*)&As2[kk][ty << 2];
            float4 bv2 = *(const float4*)&Bs2[kk][tx << 2];
            float c_[4] = {av2.x, av2.y, av2.z, av2.w};
            float d_[4] = {bv2.x, bv2.y, bv2.z, bv2.w};
            #pragma unroll
            for (int i = 0; i < 4; ++i)
                #pragma unroll
                for (int j = 0; j < 4; ++j)
                    acc[i][j] += c_[i] * d_[j];
        }
        __syncthreads();
    }

    #pragma unroll
    for (int i = 0; i < 4; ++i) {
        int row = row0 + (ty << 2) + i;
        float vv[4];
        #pragma unroll
        for (int j = 0; j < 4; ++j) {
            int col = col0 + (tx << 2) + j;
            vv[j] = acc[i][j] + bias[col];
        }
        float4 o; o.x = vv[0]; o.y = vv[1]; o.z = vv[2]; o.w = vv[3];
        *(float4*)&C[(size_t)row * NO + col0 + (tx << 2)] = o;
    }
}

// ---------- scatter softmax; also emits sa[b] = S/(S+1e-6) ----------
__global__ __launch_bounds__(64) void seg_softmax_k(const float* __restrict__ pre,
        const int* __restrict__ starts, float* __restrict__ alpha, float* __restrict__ sa)
{
    int b = blockIdx.x, lane = threadIdx.x;
    int s = starts[b], e = starts[b + 1];
    float m = -INFINITY;
    for (int i = s + lane; i < e; i += 64) m = fmaxf(m, pre[i]);
    #pragma unroll
    for (int off = 32; off; off >>= 1) m = fmaxf(m, __shfl_xor(m, off));
    float S = 0.f;
    for (int i = s + lane; i < e; i += 64) S += expf(pre[i] - m);
    #pragma unroll
    for (int off = 32; off; off >>= 1) S += __shfl_xor(S, off);
    float denom = S + 1e-6f;
    if (lane == 0) sa[b] = S / denom;
    for (int i = s + lane; i < e; i += 64) alpha[i] = expf(pre[i] - m) / denom;
}

// ---------- hw[b,:] = sum h1[i,:]*alpha[i], 16B/lane ----------
__global__ __launch_bounds__(256) void seg_wsum8(const ushort* __restrict__ raw,
        const float* __restrict__ alpha, const int* __restrict__ starts,
        float* __restrict__ vec)
{
    __shared__ float part[8][HDIM];
    const int b = blockIdx.x, tid = threadIdx.x;
    const int sub = tid & 31, r = tid >> 5;
    const int s = starts[b], e = starts[b + 1];
    float a[8] = {};
    for (int i = s + r; i < e; i += 8) {
        float al = alpha[i];
        uint4 v = *(const uint4*)&raw[(size_t)i * HDIM + sub * 8];
        a[0] += bf2f((ushort)v.x) * al;        a[1] += bf2f((ushort)(v.x >> 16)) * al;
        a[2] += bf2f((ushort)v.y) * al;        a[3] += bf2f((ushort)(v.y >> 16)) * al;
        a[4] += bf2f((ushort)v.z) * al;        a[5] += bf2f((ushort)(v.z >> 16)) * al;
        a[6] += bf2f((ushort)v.w) * al;        a[7] += bf2f((ushort)(v.w >> 16)) * al;
    }
    #pragma unroll
    for (int j = 0; j < 8; ++j) part[r][sub * 8 + j] = a[j];
    __syncthreads();
    float res = 0.f;
    #pragma unroll
    for (int j = 0; j < 8; ++j) res += part[j][tid];
    vec[(size_t)b * HDIM + tid] = res;
}

// ---------- final: vector = hw@raw_W2 + raw_b2*sa; affinity head ----------
__global__ __launch_bounds__(256) void final_k(
    const float* __restrict__ hw, const float* __restrict__ sa,
    const float* __restrict__ W2r, const float* __restrict__ rb2,
    const float* __restrict__ oW1, const float* __restrict__ ob1,
    const float* __restrict__ oW2, const float* __restrict__ ob2,
    float* __restrict__ out_vec, float* __restrict__ out_aff)
{
    __shared__ float v[HDIM];
    __shared__ float vecs[HDIM];
    __shared__ float red[4];
    int b = blockIdx.x, t = threadIdx.x;
    v[t] = hw[(size_t)b * HDIM + t];
    __syncthreads();
    float a = rb2[t] * sa[b];
    #pragma unroll 8
    for (int k = 0; k < HDIM; ++k) a += v[k] * W2r[(size_t)k * HDIM + t];
    out_vec[(size_t)b * HDIM + t] = a;
    vecs[t] = a;
    __syncthreads();
    float h = ob1[t];
    #pragma unroll 8
    for (int k = 0; k < HDIM; ++k) h += vecs[k] * oW1[(size_t)k * HDIM + t];
    h = leaky(h);
    float p = h * oW2[t];
    #pragma unroll
    for (int off = 32; off; off >>= 1) p += __shfl_down(p, off);
    int lane = t & 63, wid = t >> 6;
    if (lane == 0) red[wid] = p;
    __syncthreads();
    if (t == 0) out_aff[b] = red[0] + red[1] + red[2] + red[3] + ob2[0];
}

extern "C" void kernel_launch(void* const* d_in, const int* in_sizes, int n_in,
                              void* d_out, int out_size, void* d_ws, size_t ws_size,
                              hipStream_t stream)
{
    const int N = in_sizes[2];
    const int H = HDIM;
    const int B = BSEG;

    const float* comp   = (const float*)d_in[0];
    const float* prot   = (const float*)d_in[1];
    const int*   bc     = (const int*)d_in[2];
    const int*   bp     = (const int*)d_in[3];
    const float* c_aff_W = (const float*)d_in[4];
    const float* c_aff_b = (const float*)d_in[5];
    const float* c_sup_W = (const float*)d_in[6];
    const float* c_sup_b = (const float*)d_in[7];
    const float* p_aff_W = (const float*)d_in[8];
    const float* p_aff_b = (const float*)d_in[9];
    const float* raw_W1  = (const float*)d_in[10];
    const float* raw_b1  = (const float*)d_in[11];
    const float* raw_W2  = (const float*)d_in[12];
    const float* raw_b2  = (const float*)d_in[13];
    const float* alpha_W1 = (const float*)d_in[14];
    const float* alpha_b1 = (const float*)d_in[15];
    const float* alpha_W2 = (const float*)d_in[16];
    const float* out_W1  = (const float*)d_in[18];
    const float* out_b1  = (const float*)d_in[19];
    const float* out_W2  = (const float*)d_in[20];
    const float* out_b2  = (const float*)d_in[21];

    const size_t NBIG = (size_t)N * H;
    const size_t SSEG = (size_t)B * H;

    char* p = (char*)d_ws;
    ushort* e1 = (ushort*)p; p += NBIG * 2;   // comp_emb bf16
    ushort* h1 = (ushort*)p; p += NBIG * 2;   // hid_raw bf16
    float* supe = (float*)p;  p += SSEG * 4;
    float* pool = (float*)p;  p += SSEG * 4;
    int*  pooli = (int*)p;    p += SSEG * 4;
    float* gr   = (float*)p;  p += SSEG * 4;
    float* ga   = (float*)p;  p += SSEG * 4;
    float* hw   = (float*)p;  p += SSEG * 4;
    float* sa   = (float*)p;  p += (size_t)B * 4;
    float* pre  = (float*)p;  p += (size_t)N * 4;
    ushort* WT1 = (ushort*)p; p += (size_t)512 * 256 * 2;  // [c_aff^T ; c_sup^T]
    ushort* WTp = (ushort*)p; p += (size_t)256 * 256 * 2;  // p_aff^T
    ushort* WT2 = (ushort*)p; p += (size_t)512 * 256 * 2;  // [raw_W1[0:256]^T ; alpha_W1[0:256]^T]
    int* sc = (int*)p; p += (size_t)(B + 1) * 4;
    int* sp = (int*)p; p += (size_t)(B + 1) * 4;
    if ((size_t)(p - (char*)d_ws) > ws_size) return;

    float* out_vec   = (float*)d_out;
    float* out_alpha = out_vec + SSEG;
    float* out_aff   = out_alpha + N;

    dim3 blk(256), blk5(512);

    seg_bounds_k<<<(2 * (B + 1) + 255) / 256, blk, 0, stream>>>(bc, bp, sc, sp, N, B);
    wt_cast_all<<<5 * 16, blk, 0, stream>>>(
        c_aff_W, c_sup_W, p_aff_W, raw_W1, alpha_W1,
        WT1, WT1 + 65536, WTp, WT2, WT2 + 65536);
    init_red_k<<<(int)(SSEG / 256), blk, 0, stream>>>(supe, pooli);

    // G1: cb0: e1 = leaky(comp@c_aff+b); cb1: segment_sum(leaky(comp@c_sup+b)) -> supe
    mgx<0><<<dim3(N / 128 * 2), blk5, 0, stream>>>(
        comp, WT1, c_aff_b, c_sup_b, nullptr, nullptr, bc, e1, supe, nullptr, nullptr, nullptr);
    // G2: segment_max(leaky(prot@p_aff+b)) -> pooli
    mgx<1><<<dim3(N / 128), blk5, 0, stream>>>(
        prot, WTp, p_aff_b, nullptr, nullptr, nullptr, bp, nullptr, nullptr, pooli, nullptr, nullptr);
    unmap_pool_k<<<(int)(SSEG / 256), blk, 0, stream>>>(pooli, pool);
    // gr/ga = supe@W1[256:512] + pool@W1[512:768] + b1
    gemm64_2<<<dim3(B / 64, 4, 2), blk, 0, stream>>>(supe, pool,
        raw_W1 + H * H, raw_W1 + 2 * H * H, raw_b1,
        alpha_W1 + H * H, alpha_W1 + 2 * H * H, alpha_b1, gr, ga);
    // G3: cb0: h1 = leaky(e1@W1r + gr[bc]);  cb1: alpha-dot -> pre
    mgx<2><<<dim3(N / 128 * 2), blk5, 0, stream>>>(
        e1, WT2, nullptr, nullptr, gr, ga, bc, h1, nullptr, nullptr, alpha_W2, pre);
    // softmax -> alpha + sa  (alpha_b2 cancels exactly)
    seg_softmax_k<<<B, dim3(64), 0, stream>>>(pre, sc, out_alpha, sa);
    // hw = seg_wsum(alpha * h1)
    seg_wsum8<<<B, blk, 0, stream>>>(h1, out_alpha, sc, hw);
    // vector = hw @ raw_W2 + raw_b2*sa ; affinity head
    final_k<<<B, blk, 0, stream>>>(hw, sa, raw_W2, raw_b2,
        out_W1, out_b1, out_W2, out_b2, out_vec, out_aff);
}